// Round 1
// baseline (114.383 us; speedup 1.0000x reference)
//
#include <hip/hip_runtime.h>

#define BB 32
#define MM 512
#define SS 10
#define VV 32000
#define DD 128
#define HOPS 3

// ---------------- init: u = hidden ----------------
__global__ __launch_bounds__(256) void init_u(const float* __restrict__ hidden,
                                              float* __restrict__ u) {
    int i = blockIdx.x * 256 + threadIdx.x;
    if (i < BB * DD) u[i] = hidden[i];
}

// ---------------- logit[b,m] = sum_s dot(C_h[story[b,m,s]], u[b]) ----------------
// one wave per (b,m); lane l covers d = 2l, 2l+1 (float2)
__global__ __launch_bounds__(256) void logit_kernel(const int* __restrict__ story,
                                                    const float* __restrict__ Ch,
                                                    const float* __restrict__ u,
                                                    float* __restrict__ logit) {
    int wid = (blockIdx.x * 256 + threadIdx.x) >> 6;   // 0 .. B*M-1
    int lane = threadIdx.x & 63;
    if (wid >= BB * MM) return;
    int b = wid >> 9;                                   // M = 512
    const int* st = story + (size_t)wid * SS;

    int tok[SS];
#pragma unroll
    for (int s = 0; s < SS; ++s) tok[s] = st[s];

    float ax = 0.f, ay = 0.f;
#pragma unroll
    for (int s = 0; s < SS; ++s) {
        const float2 v = ((const float2*)(Ch + (size_t)tok[s] * DD))[lane];
        ax += v.x; ay += v.y;
    }
    const float2 uv = ((const float2*)(u + b * DD))[lane];
    float p = ax * uv.x + ay * uv.y;
#pragma unroll
    for (int off = 32; off; off >>= 1) p += __shfl_down(p, off, 64);
    if (lane == 0) logit[wid] = p;
}

// ---------------- softmax over M per b ----------------
__global__ __launch_bounds__(256) void softmax_kernel(const float* __restrict__ logit,
                                                      float* __restrict__ prob) {
    int b = blockIdx.x;
    int t = threadIdx.x;
    __shared__ float red[8];
    float l0 = logit[b * MM + t];
    float l1 = logit[b * MM + 256 + t];
    float mx = fmaxf(l0, l1);
#pragma unroll
    for (int off = 32; off; off >>= 1) mx = fmaxf(mx, __shfl_xor(mx, off, 64));
    if ((t & 63) == 0) red[t >> 6] = mx;
    __syncthreads();
    mx = fmaxf(fmaxf(red[0], red[1]), fmaxf(red[2], red[3]));
    float e0 = expf(l0 - mx), e1 = expf(l1 - mx);
    float s = e0 + e1;
#pragma unroll
    for (int off = 32; off; off >>= 1) s += __shfl_xor(s, off, 64);
    if ((t & 63) == 0) red[4 + (t >> 6)] = s;
    __syncthreads();
    s = red[4] + red[5] + red[6] + red[7];
    float inv = 1.0f / s;
    prob[b * MM + t] = e0 * inv;
    prob[b * MM + 256 + t] = e1 * inv;
}

// ---------------- partial[b,c,d] = sum_{m in chunk c} prob[b,m] * sum_s C_{h+1}[tok][d] ----------------
// block = 4 waves; wave w takes m = c*chunk + w, step 4; lane covers float2 at d=2l
__global__ __launch_bounds__(256) void partial_kernel(const int* __restrict__ story,
                                                      const float* __restrict__ Ch1,
                                                      const float* __restrict__ prob,
                                                      float* __restrict__ partial,
                                                      int chunk) {
    int b = blockIdx.y, c = blockIdx.x;
    int w = threadIdx.x >> 6, lane = threadIdx.x & 63;
    int m0 = c * chunk;
    float ax = 0.f, ay = 0.f;
    for (int m = m0 + w; m < m0 + chunk; m += 4) {
        float pw = prob[b * MM + m];
        const int* st = story + (size_t)(b * MM + m) * SS;
        int tok[SS];
#pragma unroll
        for (int s = 0; s < SS; ++s) tok[s] = st[s];
        float sx = 0.f, sy = 0.f;
#pragma unroll
        for (int s = 0; s < SS; ++s) {
            const float2 v = ((const float2*)(Ch1 + (size_t)tok[s] * DD))[lane];
            sx += v.x; sy += v.y;
        }
        ax += pw * sx; ay += pw * sy;
    }
    __shared__ float redx[4][64];
    __shared__ float redy[4][64];
    redx[w][lane] = ax;
    redy[w][lane] = ay;
    __syncthreads();
    if (w == 0) {
        float ox = redx[0][lane] + redx[1][lane] + redx[2][lane] + redx[3][lane];
        float oy = redy[0][lane] + redy[1][lane] + redy[2][lane] + redy[3][lane];
        float2* dst = (float2*)(partial + ((size_t)b * gridDim.x + c) * DD);
        dst[lane] = make_float2(ox, oy);
    }
}

// ---------------- u[b,d] += sum_c partial[b,c,d] ----------------
__global__ __launch_bounds__(256) void update_kernel(const float* __restrict__ partial,
                                                     float* __restrict__ u, int NC) {
    int i = blockIdx.x * 256 + threadIdx.x;   // b*128 + d
    if (i >= BB * DD) return;
    int b = i >> 7, d = i & 127;
    float s = 0.f;
    for (int c = 0; c < NC; ++c) s += partial[((size_t)b * NC + c) * DD + d];
    u[i] += s;
}

extern "C" void kernel_launch(void* const* d_in, const int* in_sizes, int n_in,
                              void* d_out, int out_size, void* d_ws, size_t ws_size,
                              hipStream_t stream) {
    const int*   story  = (const int*)d_in[0];
    const float* hidden = (const float*)d_in[1];
    const float* Cmat   = (const float*)d_in[2];

    float* out   = (float*)d_out;
    float* logit = out;              // first B*M floats of output = final prob_logit
    float* u     = out + BB * MM;    // tail B*D floats of output = final u

    // workspace: prob (B*M floats) then partial (B*NC*D floats)
    float* prob = (float*)d_ws;
    int NC = 32;
    while (NC > 1 && (size_t)(BB * MM + BB * NC * DD) * 4 > ws_size) NC >>= 1;
    float* partial = prob + BB * MM;
    int chunk = MM / NC;

    init_u<<<(BB * DD + 255) / 256, 256, 0, stream>>>(hidden, u);

    for (int h = 0; h < HOPS; ++h) {
        const float* Ca = Cmat + (size_t)h * VV * DD;
        const float* Cc = Cmat + (size_t)(h + 1) * VV * DD;
        logit_kernel<<<(BB * MM) / 4, 256, 0, stream>>>(story, Ca, u, logit);
        softmax_kernel<<<BB, 256, 0, stream>>>(logit, prob);
        partial_kernel<<<dim3(NC, BB), 256, 0, stream>>>(story, Cc, prob, partial, chunk);
        update_kernel<<<(BB * DD + 255) / 256, 256, 0, stream>>>(partial, u, NC);
    }
}